// Round 3
// baseline (273.770 us; speedup 1.0000x reference)
//
#include <hip/hip_runtime.h>
#include <cstdint>

#define BB 16
#define MM 128
#define TT 12000
constexpr int BT = BB * TT; // 192000

// K1: per-column stats over the M axis, sequential in m to match the
// reference reduction order. asm barriers block fma contraction.
__global__ void k1_colstats(const float* __restrict__ mel,
                            float* __restrict__ ssq,
                            float* __restrict__ dotv,
                            float* __restrict__ cmean) {
    const int b = blockIdx.y;
    const int t = blockIdx.x * blockDim.x + threadIdx.x;
    if (t >= TT) return;
    const float* base = mel + (size_t)b * MM * TT;
    float accd = 0.f, accq = 0.f, accs = 0.f;
#pragma unroll 4
    for (int m = 0; m < MM; ++m) {
        const float* rowp = base + (size_t)m * TT;
        float cur = rowp[t];
        float prev = (t > 0) ? rowp[t - 1] : 0.f;
        float p = prev * cur; asm volatile("" : "+v"(p));
        accd += p;
        float q = cur * cur;  asm volatile("" : "+v"(q));
        accq += q;
        accs += cur;
    }
    size_t i = (size_t)b * TT + t;
    ssq[i] = accq; dotv[i] = accd; cmean[i] = accs * (1.0f / MM);
}

// K_row: one block per row. Fuses temporal, cons, serial cumsum
// (LDS-resident, register-prefetch-pipelined), and the 5-iter sim.
// All arithmetic orders bitwise identical to the passing round-2 kernel;
// only the cumsum operand feed is pipelined (same add sequence).
__global__ void __launch_bounds__(256)
k_row(const float* __restrict__ ssq,
      const float* __restrict__ dotv,
      const float* __restrict__ spec,
      const float* __restrict__ cmean,
      const float* __restrict__ wraw,
      const float* __restrict__ init,
      float* __restrict__ stepv,
      float* __restrict__ candf,
      unsigned int* __restrict__ counts) {
    const int b = blockIdx.x;
    const int tid = threadIdx.x;
    __shared__ __align__(16) float buf[TT];   // cmean -> cons -> incl-cumsum (in place)
    __shared__ float red[256];
    __shared__ float mean_s, temp_s;
    __shared__ unsigned scnt[5];

    // ---- Phase A: stage cmean row, temporal = 1 - std(smooth, ddof=1) ----
    const float* crow = cmean + (size_t)b * TT;
    for (int t = tid; t < TT; t += 256) buf[t] = crow[t];
    if (tid < 5) scnt[tid] = 0u;
    __syncthreads();

    float s = 0.f;
    for (int t = tid; t < TT; t += 256) {
        float v = 0.f;
        int lo = t - 2 < 0 ? 0 : t - 2;
        int hi = t + 2 >= TT ? TT - 1 : t + 2;
        for (int j = lo; j <= hi; ++j) v += buf[j];
        s += v / 5.0f;
    }
    red[tid] = s; __syncthreads();
    for (int o = 128; o > 0; o >>= 1) {
        if (tid < o) red[tid] += red[tid + o];
        __syncthreads();
    }
    if (tid == 0) mean_s = red[0] / (float)TT;
    __syncthreads();
    float mean = mean_s;
    float ss = 0.f;
    for (int t = tid; t < TT; t += 256) {
        float v = 0.f;
        int lo = t - 2 < 0 ? 0 : t - 2;
        int hi = t + 2 >= TT ? TT - 1 : t + 2;
        for (int j = lo; j <= hi; ++j) v += buf[j];
        float sm = v / 5.0f - mean;
        ss += sm * sm;
    }
    red[tid] = ss; __syncthreads();
    for (int o = 128; o > 0; o >>= 1) {
        if (tid < o) red[tid] += red[tid + o];
        __syncthreads();
    }
    if (tid == 0) {
        float var = red[0] / (float)(TT - 1);
        temp_s = 1.0f - sqrtf(var);
    }
    __syncthreads();

    // ---- Phase B: cons row into buf (overwrite cmean), cand bits in regs ----
    float x0 = wraw[0], x1 = wraw[1], x2 = wraw[2];
    float mx = fmaxf(x0, fmaxf(x1, x2));
    float e0 = expf(x0 - mx), e1 = expf(x1 - mx), e2 = expf(x2 - mx);
    float es = (e0 + e1) + e2;
    float w0 = e0 / es, w1 = e1 / es, w2 = e2 / es;
    float temporal = temp_s;

    const float* sqr = ssq  + (size_t)b * TT;
    const float* dtr = dotv + (size_t)b * TT;
    const float* spr = spec + (size_t)b * TT;
    for (int t = tid; t < TT; t += 256) {
        float mel_sim, spec_sim;
        if (t == 0) { mel_sim = 0.f; spec_sim = 1.f; }
        else {
            float na = fmaxf(sqrtf(sqr[t - 1]), 1e-8f);
            float nb = fmaxf(sqrtf(sqr[t]),     1e-8f);
            float den = na * nb; asm volatile("" : "+v"(den));
            mel_sim = dtr[t] / den;
            float d = fabsf(spr[t] - spr[t - 1]);
            spec_sim = 1.0f / (1.0f + d);
        }
        float pa = w0 * mel_sim;  asm volatile("" : "+v"(pa));
        float pb = w1 * spec_sim; asm volatile("" : "+v"(pb));
        float pc = w2 * temporal; asm volatile("" : "+v"(pc));
        buf[t] = (pa + pb) + pc;
    }
    __syncthreads();

    unsigned long long candbits = 0ull;
    {
        int k = 0;
        for (int t = tid; t < TT; t += 256, ++k) {
            float g = (t == 0) ? 0.f : fabsf(buf[t] - buf[t - 1]);
            if (g > 0.15f) candbits |= (1ull << k);
        }
    }
    __syncthreads();

    // ---- Phase C: serial in-place inclusive cumsum (bitwise f32 chain),
    //      operand feed pipelined with an 8-deep float4 prefetch ring. ----
    if (tid == 0) {
        float4* p4 = (float4*)buf;
        constexpr int NV = TT / 4;   // 3000
        constexpr int PF = 8;        // 3000 % 8 == 0
        float4 pre[PF];
#pragma unroll
        for (int k = 0; k < PF; ++k) pre[k] = p4[k];
        float acc = 0.f;
        for (int g = 0; g < NV; g += PF) {
#pragma unroll
            for (int k = 0; k < PF; ++k) {
                float4 v = pre[k];
                int src = g + PF + k;
                if (src >= NV) src = NV - 1;   // clamped dummy prefetch at tail
                pre[k] = p4[src];
                acc += v.x; v.x = acc;
                acc += v.y; v.y = acc;
                acc += v.z; v.z = acc;
                acc += v.w; v.w = acc;
                p4[g + k] = v;
            }
        }
    }
    __syncthreads();

    // ---- Phase D: local/step + 5-iter never-done sim + exact counts ----
    const float* irow = init + (size_t)b * TT;
    unsigned nzc[5] = {0u, 0u, 0u, 0u, 0u};
    {
        int k = 0;
        for (int t = tid; t < TT; t += 256, ++k) {
            int lo = t - 2; if (lo < 0) lo = 0;
            int hi = t + 3; if (hi > TT) hi = TT;
            float csH = buf[hi - 1];                       // == CS[hi]
            float csL = (lo > 0) ? buf[lo - 1] : 0.f;      // == CS[lo]
            float local = (csH - csL) / (float)(hi - lo);
            float dir = (local > 0.7f) ? -0.1f : ((local < 0.4f) ? 0.1f : 0.0f);
            bool interior = (t >= 1) && (t <= TT - 2);
            float step = interior ? dir : 0.0f;
            float cand = ((candbits >> k) & 1ull) ? 1.f : 0.f;
            float r = irow[t];
#pragma unroll
            for (int j = 0; j < 5; ++j) {
                float adj = (fmaxf(cand, r) > 0.5f) ? step : 0.0f;
                if (adj != 0.0f) nzc[j]++;
                r = fminf(fmaxf(r + adj, 0.0f), 1.0f);
            }
            size_t idx = (size_t)b * TT + t;
            stepv[idx] = step; candf[idx] = cand;
        }
    }
#pragma unroll
    for (int j = 0; j < 5; ++j) {
        if (nzc[j]) atomicAdd(&scnt[j], nzc[j]);
    }
    __syncthreads();
    if (tid < 5 && scnt[tid]) atomicAdd(&counts[tid], scnt[tid]);
}

// K_final: freeze at the first iteration whose global adjustment count is 0.
__global__ void k_final(const float* __restrict__ init,
                        const float* __restrict__ stepv,
                        const float* __restrict__ candf,
                        const unsigned int* __restrict__ counts,
                        float* __restrict__ outp) {
    const int idx = blockIdx.x * 256 + threadIdx.x;
    float r = init[idx];
    float step = stepv[idx];
    float cand = candf[idx];
    unsigned c[5];
#pragma unroll
    for (int j = 0; j < 5; ++j) c[j] = counts[j];
#pragma unroll
    for (int j = 0; j < 5; ++j) {
        if (c[j] == 0u) break;
        float adj = (fmaxf(cand, r) > 0.5f) ? step : 0.0f;
        r = fminf(fmaxf(r + adj, 0.0f), 1.0f);
    }
    outp[idx] = r;
}

extern "C" void kernel_launch(void* const* d_in, const int* in_sizes, int n_in,
                              void* d_out, int out_size, void* d_ws, size_t ws_size,
                              hipStream_t stream) {
    const float* mel  = (const float*)d_in[0];
    const float* spec = (const float*)d_in[1];
    const float* init = (const float*)d_in[2];
    const float* wts  = (const float*)d_in[3];

    float* ws = (float*)d_ws;
    float* ssq   = ws;                 // 192000
    float* dotv  = ws + 192000;        // 192000
    float* cmean = ws + 384000;        // 192000
    float* stepv = ws + 576000;        // 192000
    float* candf = ws + 768000;        // 192000
    unsigned int* counts = (unsigned int*)(ws + 960000); // 8 u32

    hipMemsetAsync(counts, 0, 8 * sizeof(unsigned int), stream);

    dim3 g1((TT + 255) / 256, BB);
    k1_colstats<<<g1, 256, 0, stream>>>(mel, ssq, dotv, cmean);
    k_row<<<BB, 256, 0, stream>>>(ssq, dotv, spec, cmean, wts, init,
                                  stepv, candf, counts);
    k_final<<<BT / 256, 256, 0, stream>>>(init, stepv, candf, counts, (float*)d_out);
}

// Round 5
// 241.458 us; speedup vs baseline: 1.1338x; 1.1338x over previous
//
#include <hip/hip_runtime.h>
#include <cstdint>

#define BB 16
#define MM 128
#define TT 12000
constexpr int BT = BB * TT; // 192000

// K1: per-column stats over the M axis, sequential in m to match the
// reference reduction order. Each thread owns 4 adjacent columns (one
// float4 load + one scalar prev load per m). Per-column op order and the
// mul/add split (asm barriers block fmac contraction) are unchanged.
__global__ void k1_colstats(const float* __restrict__ mel,
                            float* __restrict__ ssq,
                            float* __restrict__ dotv,
                            float* __restrict__ cmean) {
    const int b = blockIdx.y;
    const int t4 = blockIdx.x * blockDim.x + threadIdx.x;
    if (t4 >= TT / 4) return;
    const int t = t4 * 4;
    const float* base = mel + (size_t)b * MM * TT;
    float accd0 = 0.f, accd1 = 0.f, accd2 = 0.f, accd3 = 0.f;
    float accq0 = 0.f, accq1 = 0.f, accq2 = 0.f, accq3 = 0.f;
    float accs0 = 0.f, accs1 = 0.f, accs2 = 0.f, accs3 = 0.f;
    for (int m = 0; m < MM; ++m) {
        const float* rowp = base + (size_t)m * TT;
        float4 cur = *(const float4*)(rowp + t);
        float prev = (t > 0) ? rowp[t - 1] : 0.f;
        float p, q;
        p = prev  * cur.x; asm volatile("" : "+v"(p)); accd0 += p;
        q = cur.x * cur.x; asm volatile("" : "+v"(q)); accq0 += q;
        accs0 += cur.x;
        p = cur.x * cur.y; asm volatile("" : "+v"(p)); accd1 += p;
        q = cur.y * cur.y; asm volatile("" : "+v"(q)); accq1 += q;
        accs1 += cur.y;
        p = cur.y * cur.z; asm volatile("" : "+v"(p)); accd2 += p;
        q = cur.z * cur.z; asm volatile("" : "+v"(q)); accq2 += q;
        accs2 += cur.z;
        p = cur.z * cur.w; asm volatile("" : "+v"(p)); accd3 += p;
        q = cur.w * cur.w; asm volatile("" : "+v"(q)); accq3 += q;
        accs3 += cur.w;
    }
    size_t i = (size_t)b * TT + t;
    *(float4*)(ssq  + i) = make_float4(accq0, accq1, accq2, accq3);
    *(float4*)(dotv + i) = make_float4(accd0, accd1, accd2, accd3);
    *(float4*)(cmean + i) = make_float4(accs0 * (1.0f / MM), accs1 * (1.0f / MM),
                                        accs2 * (1.0f / MM), accs3 * (1.0f / MM));
}

// Phase-C asm: one float4 group = counted wait, 4 dependent adds (bitwise
// the reference cumsum chain), carry snapshot to v43 BEFORE the prefetch
// read can touch the ring regs (fixes the round-4 carry race), write-back,
// prefetch read 4 groups (64 B) ahead. v40=rd addr, v41=wr addr, v43=carry.
#define GRP(R0, R1, R2, R3, OFF, W) \
    "s_waitcnt lgkmcnt(" W ")\n\t" \
    "v_add_f32 v" R0 ", v43, v" R0 "\n\t" \
    "v_add_f32 v" R1 ", v" R0 ", v" R1 "\n\t" \
    "v_add_f32 v" R2 ", v" R1 ", v" R2 "\n\t" \
    "v_add_f32 v" R3 ", v" R2 ", v" R3 "\n\t" \
    "v_mov_b32 v43, v" R3 "\n\t" \
    "ds_write_b128 v41, v[" R0 ":" R3 "] offset:" OFF "\n\t" \
    "ds_read_b128 v[" R0 ":" R3 "], v40 offset:" OFF "\n\t"

#define GRPL(R0, R1, R2, R3, OFF, W) \
    GRP(R0, R1, R2, R3, OFF, W) \
    "v_add_u32 v40, 64, v40\n\t" \
    "v_add_u32 v41, 64, v41\n\t"

// K_row: one block per row. Fuses temporal, cons, serial cumsum
// (LDS-resident, asm-pipelined), and the 5-iter sim. All FP orders
// bitwise identical to the passing round-2 kernel.
__global__ void __launch_bounds__(256)
k_row(const float* __restrict__ ssq,
      const float* __restrict__ dotv,
      const float* __restrict__ spec,
      const float* __restrict__ cmean,
      const float* __restrict__ wraw,
      const float* __restrict__ init,
      float* __restrict__ stepv,
      float* __restrict__ candf,
      unsigned int* __restrict__ counts) {
    const int b = blockIdx.x;
    const int tid = threadIdx.x;
    __shared__ __align__(16) float buf[TT];   // cmean -> cons -> incl-cumsum (in place)
    __shared__ float red[256];                // also absorbs tail prefetch over-read
    __shared__ float mean_s, temp_s;
    __shared__ unsigned scnt[5];

    // ---- Phase A: stage cmean row, temporal = 1 - std(smooth, ddof=1) ----
    const float* crow = cmean + (size_t)b * TT;
    for (int t = tid; t < TT; t += 256) buf[t] = crow[t];
    if (tid < 5) scnt[tid] = 0u;
    __syncthreads();

    float s = 0.f;
    for (int t = tid; t < TT; t += 256) {
        float v = 0.f;
        int lo = t - 2 < 0 ? 0 : t - 2;
        int hi = t + 2 >= TT ? TT - 1 : t + 2;
        for (int j = lo; j <= hi; ++j) v += buf[j];
        s += v / 5.0f;
    }
    red[tid] = s; __syncthreads();
    for (int o = 128; o > 0; o >>= 1) {
        if (tid < o) red[tid] += red[tid + o];
        __syncthreads();
    }
    if (tid == 0) mean_s = red[0] / (float)TT;
    __syncthreads();
    float mean = mean_s;
    float ss = 0.f;
    for (int t = tid; t < TT; t += 256) {
        float v = 0.f;
        int lo = t - 2 < 0 ? 0 : t - 2;
        int hi = t + 2 >= TT ? TT - 1 : t + 2;
        for (int j = lo; j <= hi; ++j) v += buf[j];
        float sm = v / 5.0f - mean;
        ss += sm * sm;
    }
    red[tid] = ss; __syncthreads();
    for (int o = 128; o > 0; o >>= 1) {
        if (tid < o) red[tid] += red[tid + o];
        __syncthreads();
    }
    if (tid == 0) {
        float var = red[0] / (float)(TT - 1);
        temp_s = 1.0f - sqrtf(var);
    }
    __syncthreads();

    // ---- Phase B: cons row into buf (overwrite cmean), cand bits in regs ----
    float x0 = wraw[0], x1 = wraw[1], x2 = wraw[2];
    float mx = fmaxf(x0, fmaxf(x1, x2));
    float e0 = expf(x0 - mx), e1 = expf(x1 - mx), e2 = expf(x2 - mx);
    float es = (e0 + e1) + e2;
    float w0 = e0 / es, w1 = e1 / es, w2 = e2 / es;
    float temporal = temp_s;

    const float* sqr = ssq  + (size_t)b * TT;
    const float* dtr = dotv + (size_t)b * TT;
    const float* spr = spec + (size_t)b * TT;
    for (int t = tid; t < TT; t += 256) {
        float mel_sim, spec_sim;
        if (t == 0) { mel_sim = 0.f; spec_sim = 1.f; }
        else {
            float na = fmaxf(sqrtf(sqr[t - 1]), 1e-8f);
            float nb = fmaxf(sqrtf(sqr[t]),     1e-8f);
            float den = na * nb; asm volatile("" : "+v"(den));
            mel_sim = dtr[t] / den;
            float d = fabsf(spr[t] - spr[t - 1]);
            spec_sim = 1.0f / (1.0f + d);
        }
        float pa = w0 * mel_sim;  asm volatile("" : "+v"(pa));
        float pb = w1 * spec_sim; asm volatile("" : "+v"(pb));
        float pc = w2 * temporal; asm volatile("" : "+v"(pc));
        buf[t] = (pa + pb) + pc;
    }
    __syncthreads();

    unsigned long long candbits = 0ull;
    {
        int k = 0;
        for (int t = tid; t < TT; t += 256, ++k) {
            float g = (t == 0) ? 0.f : fabsf(buf[t] - buf[t - 1]);
            if (g > 0.15f) candbits |= (1ull << k);
        }
    }
    __syncthreads();

    // ---- Phase C: serial in-place inclusive cumsum, asm-pipelined.
    //      Same f32 add sequence as numpy's sequential cumsum; only the
    //      DS issue schedule is pipelined (counted lgkmcnt, 4-deep ring).
    if (tid == 0) {
        uint32_t base_lds = (uint32_t)(uintptr_t)&buf[0];
        asm volatile(
            "v_mov_b32 v40, %0\n\t"
            "v_mov_b32 v41, %0\n\t"
            "v_mov_b32 v43, 0\n\t"
            "ds_read_b128 v[44:47], v40\n\t"
            "ds_read_b128 v[48:51], v40 offset:16\n\t"
            "ds_read_b128 v[52:55], v40 offset:32\n\t"
            "ds_read_b128 v[56:59], v40 offset:48\n\t"
            "v_add_u32 v40, 64, v40\n\t"
            // peeled body 0 (queue fills to steady-state depth 8)
            GRP ("44", "45", "46", "47", "0",  "3")
            GRP ("48", "49", "50", "51", "16", "4")
            GRP ("52", "53", "54", "55", "32", "5")
            GRPL("56", "57", "58", "59", "48", "6")
            "s_mov_b32 s20, 749\n\t"
            "3:\n\t"
            GRP ("44", "45", "46", "47", "0",  "6")
            GRP ("48", "49", "50", "51", "16", "6")
            GRP ("52", "53", "54", "55", "32", "6")
            GRPL("56", "57", "58", "59", "48", "6")
            "s_sub_u32 s20, s20, 1\n\t"
            "s_cmp_lg_u32 s20, 0\n\t"
            "s_cbranch_scc1 3b\n\t"
            "s_waitcnt lgkmcnt(0)\n\t"
            :
            : "v"(base_lds)
            : "v40", "v41", "v43", "v44", "v45", "v46", "v47",
              "v48", "v49", "v50", "v51", "v52", "v53", "v54", "v55",
              "v56", "v57", "v58", "v59", "s20", "scc", "memory");
    }
    __syncthreads();

    // ---- Phase D: local/step + 5-iter never-done sim + exact counts ----
    const float* irow = init + (size_t)b * TT;
    unsigned nzc[5] = {0u, 0u, 0u, 0u, 0u};
    {
        int k = 0;
        for (int t = tid; t < TT; t += 256, ++k) {
            int lo = t - 2; if (lo < 0) lo = 0;
            int hi = t + 3; if (hi > TT) hi = TT;
            float csH = buf[hi - 1];                       // == CS[hi]
            float csL = (lo > 0) ? buf[lo - 1] : 0.f;      // == CS[lo]
            float local = (csH - csL) / (float)(hi - lo);
            float dir = (local > 0.7f) ? -0.1f : ((local < 0.4f) ? 0.1f : 0.0f);
            bool interior = (t >= 1) && (t <= TT - 2);
            float step = interior ? dir : 0.0f;
            float cand = ((candbits >> k) & 1ull) ? 1.f : 0.f;
            float r = irow[t];
#pragma unroll
            for (int j = 0; j < 5; ++j) {
                float adj = (fmaxf(cand, r) > 0.5f) ? step : 0.0f;
                if (adj != 0.0f) nzc[j]++;
                r = fminf(fmaxf(r + adj, 0.0f), 1.0f);
            }
            size_t idx = (size_t)b * TT + t;
            stepv[idx] = step; candf[idx] = cand;
        }
    }
#pragma unroll
    for (int j = 0; j < 5; ++j) {
        if (nzc[j]) atomicAdd(&scnt[j], nzc[j]);
    }
    __syncthreads();
    if (tid < 5 && scnt[tid]) atomicAdd(&counts[tid], scnt[tid]);
}

// K_final: freeze at the first iteration whose global adjustment count is 0.
__global__ void k_final(const float* __restrict__ init,
                        const float* __restrict__ stepv,
                        const float* __restrict__ candf,
                        const unsigned int* __restrict__ counts,
                        float* __restrict__ outp) {
    const int idx = blockIdx.x * 256 + threadIdx.x;
    float r = init[idx];
    float step = stepv[idx];
    float cand = candf[idx];
    unsigned c[5];
#pragma unroll
    for (int j = 0; j < 5; ++j) c[j] = counts[j];
#pragma unroll
    for (int j = 0; j < 5; ++j) {
        if (c[j] == 0u) break;
        float adj = (fmaxf(cand, r) > 0.5f) ? step : 0.0f;
        r = fminf(fmaxf(r + adj, 0.0f), 1.0f);
    }
    outp[idx] = r;
}

extern "C" void kernel_launch(void* const* d_in, const int* in_sizes, int n_in,
                              void* d_out, int out_size, void* d_ws, size_t ws_size,
                              hipStream_t stream) {
    const float* mel  = (const float*)d_in[0];
    const float* spec = (const float*)d_in[1];
    const float* init = (const float*)d_in[2];
    const float* wts  = (const float*)d_in[3];

    float* ws = (float*)d_ws;
    float* ssq   = ws;                 // 192000
    float* dotv  = ws + 192000;        // 192000
    float* cmean = ws + 384000;        // 192000
    float* stepv = ws + 576000;        // 192000
    float* candf = ws + 768000;        // 192000
    unsigned int* counts = (unsigned int*)(ws + 960000); // 8 u32

    hipMemsetAsync(counts, 0, 8 * sizeof(unsigned int), stream);

    dim3 g1((TT / 4 + 255) / 256, BB);
    k1_colstats<<<g1, 256, 0, stream>>>(mel, ssq, dotv, cmean);
    k_row<<<BB, 256, 0, stream>>>(ssq, dotv, spec, cmean, wts, init,
                                  stepv, candf, counts);
    k_final<<<BT / 256, 256, 0, stream>>>(init, stepv, candf, counts, (float*)d_out);
}

// Round 6
// 240.735 us; speedup vs baseline: 1.1372x; 1.0030x over previous
//
#include <hip/hip_runtime.h>
#include <cstdint>

#define BB 16
#define MM 128
#define TT 12000
constexpr int BT = BB * TT; // 192000

// K1: per-column stats over the M axis, sequential in m to match the
// reference reduction order. Each thread owns 4 adjacent columns. Per-column
// op order and the mul/add split (asm barriers block fmac) unchanged.
__global__ void k1_colstats(const float* __restrict__ mel,
                            float* __restrict__ ssq,
                            float* __restrict__ dotv,
                            float* __restrict__ cmean) {
    const int b = blockIdx.y;
    const int t4 = blockIdx.x * blockDim.x + threadIdx.x;
    if (t4 >= TT / 4) return;
    const int t = t4 * 4;
    const float* base = mel + (size_t)b * MM * TT;
    float accd0 = 0.f, accd1 = 0.f, accd2 = 0.f, accd3 = 0.f;
    float accq0 = 0.f, accq1 = 0.f, accq2 = 0.f, accq3 = 0.f;
    float accs0 = 0.f, accs1 = 0.f, accs2 = 0.f, accs3 = 0.f;
    for (int m = 0; m < MM; ++m) {
        const float* rowp = base + (size_t)m * TT;
        float4 cur = *(const float4*)(rowp + t);
        float prev = (t > 0) ? rowp[t - 1] : 0.f;
        float p, q;
        p = prev  * cur.x; asm volatile("" : "+v"(p)); accd0 += p;
        q = cur.x * cur.x; asm volatile("" : "+v"(q)); accq0 += q;
        accs0 += cur.x;
        p = cur.x * cur.y; asm volatile("" : "+v"(p)); accd1 += p;
        q = cur.y * cur.y; asm volatile("" : "+v"(q)); accq1 += q;
        accs1 += cur.y;
        p = cur.y * cur.z; asm volatile("" : "+v"(p)); accd2 += p;
        q = cur.z * cur.z; asm volatile("" : "+v"(q)); accq2 += q;
        accs2 += cur.z;
        p = cur.z * cur.w; asm volatile("" : "+v"(p)); accd3 += p;
        q = cur.w * cur.w; asm volatile("" : "+v"(q)); accq3 += q;
        accs3 += cur.w;
    }
    size_t i = (size_t)b * TT + t;
    *(float4*)(ssq  + i) = make_float4(accq0, accq1, accq2, accq3);
    *(float4*)(dotv + i) = make_float4(accd0, accd1, accd2, accd3);
    *(float4*)(cmean + i) = make_float4(accs0 * (1.0f / MM), accs1 * (1.0f / MM),
                                        accs2 * (1.0f / MM), accs3 * (1.0f / MM));
}

// kA: temporal = 1 - std(smooth, ddof=1). Bitwise replica of the round-1
// passing k2 (reads cmean from global; same strided partials, same 256-tree).
__global__ void kA_temporal(const float* __restrict__ cmean,
                            float* __restrict__ temporal) {
    const int b = blockIdx.x;
    const float* row = cmean + (size_t)b * TT;
    __shared__ float red[256];
    __shared__ float mean_s;
    float s = 0.f;
    for (int t = threadIdx.x; t < TT; t += 256) {
        float v = 0.f;
        int lo = t - 2 < 0 ? 0 : t - 2;
        int hi = t + 2 >= TT ? TT - 1 : t + 2;
        for (int j = lo; j <= hi; ++j) v += row[j];
        s += v / 5.0f;
    }
    red[threadIdx.x] = s; __syncthreads();
    for (int o = 128; o > 0; o >>= 1) {
        if (threadIdx.x < o) red[threadIdx.x] += red[threadIdx.x + o];
        __syncthreads();
    }
    if (threadIdx.x == 0) mean_s = red[0] / (float)TT;
    __syncthreads();
    float mean = mean_s;
    float ss = 0.f;
    for (int t = threadIdx.x; t < TT; t += 256) {
        float v = 0.f;
        int lo = t - 2 < 0 ? 0 : t - 2;
        int hi = t + 2 >= TT ? TT - 1 : t + 2;
        for (int j = lo; j <= hi; ++j) v += row[j];
        float sm = v / 5.0f - mean;
        ss += sm * sm;
    }
    red[threadIdx.x] = ss; __syncthreads();
    for (int o = 128; o > 0; o >>= 1) {
        if (threadIdx.x < o) red[threadIdx.x] += red[threadIdx.x + o];
        __syncthreads();
    }
    if (threadIdx.x == 0) {
        float var = red[0] / (float)(TT - 1);
        temporal[b] = 1.0f - sqrtf(var);
    }
}

// kB: cons — bitwise replica of round-1's passing k3, now 750 blocks.
__global__ void kB_cons(const float* __restrict__ ssq,
                        const float* __restrict__ dotv,
                        const float* __restrict__ spec,
                        const float* __restrict__ temporal,
                        const float* __restrict__ wraw,
                        float* __restrict__ cons) {
    const int idx = blockIdx.x * 256 + threadIdx.x;
    const int b = idx / TT;
    const int t = idx - b * TT;
    float x0 = wraw[0], x1 = wraw[1], x2 = wraw[2];
    float mx = fmaxf(x0, fmaxf(x1, x2));
    float e0 = expf(x0 - mx), e1 = expf(x1 - mx), e2 = expf(x2 - mx);
    float es = (e0 + e1) + e2;
    float w0 = e0 / es, w1 = e1 / es, w2 = e2 / es;
    float mel_sim, spec_sim;
    if (t == 0) { mel_sim = 0.f; spec_sim = 1.f; }
    else {
        float na = fmaxf(sqrtf(ssq[idx - 1]), 1e-8f);
        float nb = fmaxf(sqrtf(ssq[idx]),     1e-8f);
        float den = na * nb; asm volatile("" : "+v"(den));
        mel_sim = dotv[idx] / den;
        float d = fabsf(spec[idx] - spec[idx - 1]);
        spec_sim = 1.0f / (1.0f + d);
    }
    float pa = w0 * mel_sim;     asm volatile("" : "+v"(pa));
    float pb = w1 * spec_sim;    asm volatile("" : "+v"(pb));
    float pc = w2 * temporal[b]; asm volatile("" : "+v"(pc));
    cons[idx] = (pa + pb) + pc;
}

// Phase-C asm (proven in round 5): counted-lgkmcnt 4-deep float4 ring,
// carry snapshot to v43 before the prefetch read. Bitwise reference chain.
#define GRP(R0, R1, R2, R3, OFF, W) \
    "s_waitcnt lgkmcnt(" W ")\n\t" \
    "v_add_f32 v" R0 ", v43, v" R0 "\n\t" \
    "v_add_f32 v" R1 ", v" R0 ", v" R1 "\n\t" \
    "v_add_f32 v" R2 ", v" R1 ", v" R2 "\n\t" \
    "v_add_f32 v" R3 ", v" R2 ", v" R3 "\n\t" \
    "v_mov_b32 v43, v" R3 "\n\t" \
    "ds_write_b128 v41, v[" R0 ":" R3 "] offset:" OFF "\n\t" \
    "ds_read_b128 v[" R0 ":" R3 "], v40 offset:" OFF "\n\t"

#define GRPL(R0, R1, R2, R3, OFF, W) \
    GRP(R0, R1, R2, R3, OFF, W) \
    "v_add_u32 v40, 64, v40\n\t" \
    "v_add_u32 v41, 64, v41\n\t"

// kC: stage cons->LDS, candbits, serial asm cumsum, Phase D.
__global__ void __launch_bounds__(256)
kC_row(const float* __restrict__ cons,
       const float* __restrict__ init,
       float* __restrict__ stepv,
       float* __restrict__ candf,
       unsigned int* __restrict__ counts) {
    const int b = blockIdx.x;
    const int tid = threadIdx.x;
    __shared__ __align__(16) float buf[TT + 16];  // +16 pads tail prefetch over-read
    __shared__ unsigned scnt[5];

    const float4* c4 = (const float4*)(cons + (size_t)b * TT);
    float4* b4 = (float4*)buf;
    for (int i = tid; i < TT / 4; i += 256) b4[i] = c4[i];
    if (tid < 5) scnt[tid] = 0u;
    __syncthreads();

    unsigned long long candbits = 0ull;
    {
        int k = 0;
        for (int t = tid; t < TT; t += 256, ++k) {
            float g = (t == 0) ? 0.f : fabsf(buf[t] - buf[t - 1]);
            if (g > 0.15f) candbits |= (1ull << k);
        }
    }
    __syncthreads();

    if (tid == 0) {
        uint32_t base_lds = (uint32_t)(uintptr_t)&buf[0];
        asm volatile(
            "v_mov_b32 v40, %0\n\t"
            "v_mov_b32 v41, %0\n\t"
            "v_mov_b32 v43, 0\n\t"
            "ds_read_b128 v[44:47], v40\n\t"
            "ds_read_b128 v[48:51], v40 offset:16\n\t"
            "ds_read_b128 v[52:55], v40 offset:32\n\t"
            "ds_read_b128 v[56:59], v40 offset:48\n\t"
            "v_add_u32 v40, 64, v40\n\t"
            GRP ("44", "45", "46", "47", "0",  "3")
            GRP ("48", "49", "50", "51", "16", "4")
            GRP ("52", "53", "54", "55", "32", "5")
            GRPL("56", "57", "58", "59", "48", "6")
            "s_mov_b32 s20, 749\n\t"
            "3:\n\t"
            GRP ("44", "45", "46", "47", "0",  "6")
            GRP ("48", "49", "50", "51", "16", "6")
            GRP ("52", "53", "54", "55", "32", "6")
            GRPL("56", "57", "58", "59", "48", "6")
            "s_sub_u32 s20, s20, 1\n\t"
            "s_cmp_lg_u32 s20, 0\n\t"
            "s_cbranch_scc1 3b\n\t"
            "s_waitcnt lgkmcnt(0)\n\t"
            :
            : "v"(base_lds)
            : "v40", "v41", "v43", "v44", "v45", "v46", "v47",
              "v48", "v49", "v50", "v51", "v52", "v53", "v54", "v55",
              "v56", "v57", "v58", "v59", "s20", "scc", "memory");
    }
    __syncthreads();

    // Phase D: local/step + 5-iter never-done sim + exact counts.
    const float* irow = init + (size_t)b * TT;
    unsigned nzc[5] = {0u, 0u, 0u, 0u, 0u};
    {
        int k = 0;
        for (int t = tid; t < TT; t += 256, ++k) {
            int lo = t - 2; if (lo < 0) lo = 0;
            int hi = t + 3; if (hi > TT) hi = TT;
            float csH = buf[hi - 1];                       // == CS[hi]
            float csL = (lo > 0) ? buf[lo - 1] : 0.f;      // == CS[lo]
            float local = (csH - csL) / (float)(hi - lo);
            float dir = (local > 0.7f) ? -0.1f : ((local < 0.4f) ? 0.1f : 0.0f);
            bool interior = (t >= 1) && (t <= TT - 2);
            float step = interior ? dir : 0.0f;
            float cand = ((candbits >> k) & 1ull) ? 1.f : 0.f;
            float r = irow[t];
#pragma unroll
            for (int j = 0; j < 5; ++j) {
                float adj = (fmaxf(cand, r) > 0.5f) ? step : 0.0f;
                if (adj != 0.0f) nzc[j]++;
                r = fminf(fmaxf(r + adj, 0.0f), 1.0f);
            }
            size_t idx = (size_t)b * TT + t;
            stepv[idx] = step; candf[idx] = cand;
        }
    }
#pragma unroll
    for (int j = 0; j < 5; ++j) {
        if (nzc[j]) atomicAdd(&scnt[j], nzc[j]);
    }
    __syncthreads();
    if (tid < 5 && scnt[tid]) atomicAdd(&counts[tid], scnt[tid]);
}

// K_final: freeze at the first iteration whose global adjustment count is 0.
__global__ void k_final(const float* __restrict__ init,
                        const float* __restrict__ stepv,
                        const float* __restrict__ candf,
                        const unsigned int* __restrict__ counts,
                        float* __restrict__ outp) {
    const int idx = blockIdx.x * 256 + threadIdx.x;
    float r = init[idx];
    float step = stepv[idx];
    float cand = candf[idx];
    unsigned c[5];
#pragma unroll
    for (int j = 0; j < 5; ++j) c[j] = counts[j];
#pragma unroll
    for (int j = 0; j < 5; ++j) {
        if (c[j] == 0u) break;
        float adj = (fmaxf(cand, r) > 0.5f) ? step : 0.0f;
        r = fminf(fmaxf(r + adj, 0.0f), 1.0f);
    }
    outp[idx] = r;
}

extern "C" void kernel_launch(void* const* d_in, const int* in_sizes, int n_in,
                              void* d_out, int out_size, void* d_ws, size_t ws_size,
                              hipStream_t stream) {
    const float* mel  = (const float*)d_in[0];
    const float* spec = (const float*)d_in[1];
    const float* init = (const float*)d_in[2];
    const float* wts  = (const float*)d_in[3];

    float* ws = (float*)d_ws;
    float* ssq   = ws;                 // 192000
    float* dotv  = ws + 192000;        // 192000
    float* cmean = ws + 384000;        // 192000
    float* cons  = ws + 576000;        // 192000
    float* stepv = ws + 768000;        // 192000
    float* candf = ws + 960000;        // 192000
    float* temporal = ws + 1152000;    // 16
    unsigned int* counts = (unsigned int*)(ws + 1152016); // 8 u32

    hipMemsetAsync(counts, 0, 8 * sizeof(unsigned int), stream);

    dim3 g1((TT / 4 + 255) / 256, BB);
    k1_colstats<<<g1, 256, 0, stream>>>(mel, ssq, dotv, cmean);
    kA_temporal<<<BB, 256, 0, stream>>>(cmean, temporal);
    kB_cons<<<BT / 256, 256, 0, stream>>>(ssq, dotv, spec, temporal, wts, cons);
    kC_row<<<BB, 256, 0, stream>>>(cons, init, stepv, candf, counts);
    k_final<<<BT / 256, 256, 0, stream>>>(init, stepv, candf, counts, (float*)d_out);
}

// Round 7
// 208.872 us; speedup vs baseline: 1.3107x; 1.1525x over previous
//
#include <hip/hip_runtime.h>
#include <cstdint>

#define BB 16
#define MM 128
#define TT 12000
constexpr int BT = BB * TT; // 192000

// K1: per-column stats over the M axis, sequential in m (reference order).
// 64-thread blocks -> 752 blocks across all CUs; unroll 4 gives load ILP
// (accumulator add order per column unchanged; asm barriers block fmac).
// Also zeroes the counts buffer (replaces the memset dispatch).
__global__ void k1_colstats(const float* __restrict__ mel,
                            float* __restrict__ ssq,
                            float* __restrict__ dotv,
                            float* __restrict__ cmean,
                            unsigned int* __restrict__ counts) {
    if (blockIdx.x == 0 && blockIdx.y == 0 && threadIdx.x < 8)
        counts[threadIdx.x] = 0u;
    const int b = blockIdx.y;
    const int t4 = blockIdx.x * blockDim.x + threadIdx.x;
    if (t4 >= TT / 4) return;
    const int t = t4 * 4;
    const float* base = mel + (size_t)b * MM * TT;
    float accd0 = 0.f, accd1 = 0.f, accd2 = 0.f, accd3 = 0.f;
    float accq0 = 0.f, accq1 = 0.f, accq2 = 0.f, accq3 = 0.f;
    float accs0 = 0.f, accs1 = 0.f, accs2 = 0.f, accs3 = 0.f;
#pragma unroll 4
    for (int m = 0; m < MM; ++m) {
        const float* rowp = base + (size_t)m * TT;
        float4 cur = *(const float4*)(rowp + t);
        float prev = (t > 0) ? rowp[t - 1] : 0.f;
        float p, q;
        p = prev  * cur.x; asm volatile("" : "+v"(p)); accd0 += p;
        q = cur.x * cur.x; asm volatile("" : "+v"(q)); accq0 += q;
        accs0 += cur.x;
        p = cur.x * cur.y; asm volatile("" : "+v"(p)); accd1 += p;
        q = cur.y * cur.y; asm volatile("" : "+v"(q)); accq1 += q;
        accs1 += cur.y;
        p = cur.y * cur.z; asm volatile("" : "+v"(p)); accd2 += p;
        q = cur.z * cur.z; asm volatile("" : "+v"(q)); accq2 += q;
        accs2 += cur.z;
        p = cur.z * cur.w; asm volatile("" : "+v"(p)); accd3 += p;
        q = cur.w * cur.w; asm volatile("" : "+v"(q)); accq3 += q;
        accs3 += cur.w;
    }
    size_t i = (size_t)b * TT + t;
    *(float4*)(ssq  + i) = make_float4(accq0, accq1, accq2, accq3);
    *(float4*)(dotv + i) = make_float4(accd0, accd1, accd2, accd3);
    *(float4*)(cmean + i) = make_float4(accs0 * (1.0f / MM), accs1 * (1.0f / MM),
                                        accs2 * (1.0f / MM), accs3 * (1.0f / MM));
}

// kA: temporal = 1 - std(smooth, ddof=1). Same arithmetic/order as the
// passing version; row staged to LDS once (was 10 global reads/element).
__global__ void kA_temporal(const float* __restrict__ cmean,
                            float* __restrict__ temporal) {
    const int b = blockIdx.x;
    const int tid = threadIdx.x;
    __shared__ __align__(16) float row_s[TT];
    __shared__ float red[256];
    __shared__ float mean_s;
    const float4* c4 = (const float4*)(cmean + (size_t)b * TT);
    float4* r4 = (float4*)row_s;
    for (int i = tid; i < TT / 4; i += 256) r4[i] = c4[i];
    __syncthreads();

    float s = 0.f;
    for (int t = tid; t < TT; t += 256) {
        float v = 0.f;
        int lo = t - 2 < 0 ? 0 : t - 2;
        int hi = t + 2 >= TT ? TT - 1 : t + 2;
        for (int j = lo; j <= hi; ++j) v += row_s[j];
        s += v / 5.0f;
    }
    red[tid] = s; __syncthreads();
    for (int o = 128; o > 0; o >>= 1) {
        if (tid < o) red[tid] += red[tid + o];
        __syncthreads();
    }
    if (tid == 0) mean_s = red[0] / (float)TT;
    __syncthreads();
    float mean = mean_s;
    float ss = 0.f;
    for (int t = tid; t < TT; t += 256) {
        float v = 0.f;
        int lo = t - 2 < 0 ? 0 : t - 2;
        int hi = t + 2 >= TT ? TT - 1 : t + 2;
        for (int j = lo; j <= hi; ++j) v += row_s[j];
        float sm = v / 5.0f - mean;
        ss += sm * sm;
    }
    red[tid] = ss; __syncthreads();
    for (int o = 128; o > 0; o >>= 1) {
        if (tid < o) red[tid] += red[tid + o];
        __syncthreads();
    }
    if (tid == 0) {
        float var = red[0] / (float)(TT - 1);
        temporal[b] = 1.0f - sqrtf(var);
    }
}

// kB: cons — bitwise replica of the passing version, 750 blocks.
__global__ void kB_cons(const float* __restrict__ ssq,
                        const float* __restrict__ dotv,
                        const float* __restrict__ spec,
                        const float* __restrict__ temporal,
                        const float* __restrict__ wraw,
                        float* __restrict__ cons) {
    const int idx = blockIdx.x * 256 + threadIdx.x;
    const int b = idx / TT;
    const int t = idx - b * TT;
    float x0 = wraw[0], x1 = wraw[1], x2 = wraw[2];
    float mx = fmaxf(x0, fmaxf(x1, x2));
    float e0 = expf(x0 - mx), e1 = expf(x1 - mx), e2 = expf(x2 - mx);
    float es = (e0 + e1) + e2;
    float w0 = e0 / es, w1 = e1 / es, w2 = e2 / es;
    float mel_sim, spec_sim;
    if (t == 0) { mel_sim = 0.f; spec_sim = 1.f; }
    else {
        float na = fmaxf(sqrtf(ssq[idx - 1]), 1e-8f);
        float nb = fmaxf(sqrtf(ssq[idx]),     1e-8f);
        float den = na * nb; asm volatile("" : "+v"(den));
        mel_sim = dotv[idx] / den;
        float d = fabsf(spec[idx] - spec[idx - 1]);
        spec_sim = 1.0f / (1.0f + d);
    }
    float pa = w0 * mel_sim;     asm volatile("" : "+v"(pa));
    float pb = w1 * spec_sim;    asm volatile("" : "+v"(pb));
    float pc = w2 * temporal[b]; asm volatile("" : "+v"(pc));
    cons[idx] = (pa + pb) + pc;
}

// Chain quad: 4 dependent adds (bitwise reference order), carry snapshot,
// CS write to LDS, reload this quad's ring slot from global 3 batches ahead.
// v40 = global byte offset, v41 = LDS byte addr, v43 = carry.
#define CQ(R0, R1, R2, R3, OFF) \
    "v_add_f32 v" R0 ", v43, v" R0 "\n\t" \
    "v_add_f32 v" R1 ", v" R0 ", v" R1 "\n\t" \
    "v_add_f32 v" R2 ", v" R1 ", v" R2 "\n\t" \
    "v_add_f32 v" R3 ", v" R2 ", v" R3 "\n\t" \
    "v_mov_b32 v43, v" R3 "\n\t" \
    "ds_write_b128 v41, v[" R0 ":" R3 "] offset:" OFF "\n\t" \
    "global_load_dwordx4 v[" R0 ":" R3 "], v40, %1 offset:" OFF "\n\t"

// kC: candbits from global cons; serial cumsum (global->regs->LDS CS,
// 12-quad ring, one vmcnt wait per 16 elems); Phase D from LDS CS.
__global__ void __launch_bounds__(256)
kC_row(const float* __restrict__ cons,
       const float* __restrict__ init,
       float* __restrict__ stepv,
       float* __restrict__ candf,
       unsigned int* __restrict__ counts) {
    const int b = blockIdx.x;
    const int tid = threadIdx.x;
    __shared__ __align__(16) float buf[TT + 16];   // holds CS after the chain
    __shared__ unsigned scnt[5];

    const float* crow = cons + (size_t)b * TT;
    if (tid < 5) scnt[tid] = 0u;

    unsigned long long candbits = 0ull;
    {
        int k = 0;
        for (int t = tid; t < TT; t += 256, ++k) {
            float g = (t == 0) ? 0.f : fabsf(crow[t] - crow[t - 1]);
            if (g > 0.15f) candbits |= (1ull << k);
        }
    }

    if (tid == 0) {
        uint32_t lds_base = (uint32_t)(uintptr_t)&buf[0];
        asm volatile(
            "v_mov_b32 v40, 0\n\t"
            "v_mov_b32 v41, %0\n\t"
            "v_mov_b32 v43, 0\n\t"
            // prologue: fill 12-quad ring (batches 0..2)
            "global_load_dwordx4 v[44:47], v40, %1 offset:0\n\t"
            "global_load_dwordx4 v[48:51], v40, %1 offset:16\n\t"
            "global_load_dwordx4 v[52:55], v40, %1 offset:32\n\t"
            "global_load_dwordx4 v[56:59], v40, %1 offset:48\n\t"
            "global_load_dwordx4 v[60:63], v40, %1 offset:64\n\t"
            "global_load_dwordx4 v[64:67], v40, %1 offset:80\n\t"
            "global_load_dwordx4 v[68:71], v40, %1 offset:96\n\t"
            "global_load_dwordx4 v[72:75], v40, %1 offset:112\n\t"
            "global_load_dwordx4 v[76:79], v40, %1 offset:128\n\t"
            "global_load_dwordx4 v[80:83], v40, %1 offset:144\n\t"
            "global_load_dwordx4 v[84:87], v40, %1 offset:160\n\t"
            "global_load_dwordx4 v[88:91], v40, %1 offset:176\n\t"
            "v_mov_b32 v40, 192\n\t"
            "s_mov_b32 s20, 250\n\t"
            "3:\n\t"
            // sub-batch 0: quads 44/48/52/56, bytes v41+0..63
            "s_waitcnt vmcnt(8)\n\t"
            CQ("44", "45", "46", "47", "0")
            CQ("48", "49", "50", "51", "16")
            CQ("52", "53", "54", "55", "32")
            CQ("56", "57", "58", "59", "48")
            // sub-batch 1: quads 60/64/68/72, bytes v41+64..127
            "s_waitcnt vmcnt(8)\n\t"
            CQ("60", "61", "62", "63", "64")
            CQ("64", "65", "66", "67", "80")
            CQ("68", "69", "70", "71", "96")
            CQ("72", "73", "74", "75", "112")
            // sub-batch 2: quads 76/80/84/88, bytes v41+128..191
            "s_waitcnt vmcnt(8)\n\t"
            CQ("76", "77", "78", "79", "128")
            CQ("80", "81", "82", "83", "144")
            CQ("84", "85", "86", "87", "160")
            CQ("88", "89", "90", "91", "176")
            "v_add_u32 v40, 192, v40\n\t"
            "v_add_u32 v41, 192, v41\n\t"
            "s_sub_u32 s20, s20, 1\n\t"
            "s_cmp_lg_u32 s20, 0\n\t"
            "s_cbranch_scc1 3b\n\t"
            "s_waitcnt vmcnt(0) lgkmcnt(0)\n\t"
            :
            : "v"(lds_base), "s"(crow)
            : "v40", "v41", "v43",
              "v44", "v45", "v46", "v47", "v48", "v49", "v50", "v51",
              "v52", "v53", "v54", "v55", "v56", "v57", "v58", "v59",
              "v60", "v61", "v62", "v63", "v64", "v65", "v66", "v67",
              "v68", "v69", "v70", "v71", "v72", "v73", "v74", "v75",
              "v76", "v77", "v78", "v79", "v80", "v81", "v82", "v83",
              "v84", "v85", "v86", "v87", "v88", "v89", "v90", "v91",
              "s20", "scc", "memory");
    }
    __syncthreads();

    // Phase D: local/step + 5-iter never-done sim + exact counts.
    const float* irow = init + (size_t)b * TT;
    unsigned nzc[5] = {0u, 0u, 0u, 0u, 0u};
    {
        int k = 0;
        for (int t = tid; t < TT; t += 256, ++k) {
            int lo = t - 2; if (lo < 0) lo = 0;
            int hi = t + 3; if (hi > TT) hi = TT;
            float csH = buf[hi - 1];                       // == CS[hi]
            float csL = (lo > 0) ? buf[lo - 1] : 0.f;      // == CS[lo]
            float local = (csH - csL) / (float)(hi - lo);
            float dir = (local > 0.7f) ? -0.1f : ((local < 0.4f) ? 0.1f : 0.0f);
            bool interior = (t >= 1) && (t <= TT - 2);
            float step = interior ? dir : 0.0f;
            float cand = ((candbits >> k) & 1ull) ? 1.f : 0.f;
            float r = irow[t];
#pragma unroll
            for (int j = 0; j < 5; ++j) {
                float adj = (fmaxf(cand, r) > 0.5f) ? step : 0.0f;
                if (adj != 0.0f) nzc[j]++;
                r = fminf(fmaxf(r + adj, 0.0f), 1.0f);
            }
            size_t idx = (size_t)b * TT + t;
            stepv[idx] = step; candf[idx] = cand;
        }
    }
#pragma unroll
    for (int j = 0; j < 5; ++j) {
        if (nzc[j]) atomicAdd(&scnt[j], nzc[j]);
    }
    __syncthreads();
    if (tid < 5 && scnt[tid]) atomicAdd(&counts[tid], scnt[tid]);
}

// K_final: freeze at the first iteration whose global adjustment count is 0.
__global__ void k_final(const float* __restrict__ init,
                        const float* __restrict__ stepv,
                        const float* __restrict__ candf,
                        const unsigned int* __restrict__ counts,
                        float* __restrict__ outp) {
    const int idx = blockIdx.x * 256 + threadIdx.x;
    float r = init[idx];
    float step = stepv[idx];
    float cand = candf[idx];
    unsigned c[5];
#pragma unroll
    for (int j = 0; j < 5; ++j) c[j] = counts[j];
#pragma unroll
    for (int j = 0; j < 5; ++j) {
        if (c[j] == 0u) break;
        float adj = (fmaxf(cand, r) > 0.5f) ? step : 0.0f;
        r = fminf(fmaxf(r + adj, 0.0f), 1.0f);
    }
    outp[idx] = r;
}

extern "C" void kernel_launch(void* const* d_in, const int* in_sizes, int n_in,
                              void* d_out, int out_size, void* d_ws, size_t ws_size,
                              hipStream_t stream) {
    const float* mel  = (const float*)d_in[0];
    const float* spec = (const float*)d_in[1];
    const float* init = (const float*)d_in[2];
    const float* wts  = (const float*)d_in[3];

    float* ws = (float*)d_ws;
    float* ssq   = ws;                 // 192000
    float* dotv  = ws + 192000;        // 192000
    float* cmean = ws + 384000;        // 192000
    float* cons  = ws + 576000;        // 192000
    float* stepv = ws + 768000;        // 192000 (also absorbs chain over-read)
    float* candf = ws + 960000;        // 192000
    float* temporal = ws + 1152000;    // 16
    unsigned int* counts = (unsigned int*)(ws + 1152016); // 8 u32

    dim3 g1((TT / 4 + 63) / 64, BB);
    k1_colstats<<<g1, 64, 0, stream>>>(mel, ssq, dotv, cmean, counts);
    kA_temporal<<<BB, 256, 0, stream>>>(cmean, temporal);
    kB_cons<<<BT / 256, 256, 0, stream>>>(ssq, dotv, spec, temporal, wts, cons);
    kC_row<<<BB, 256, 0, stream>>>(cons, init, stepv, candf, counts);
    k_final<<<BT / 256, 256, 0, stream>>>(init, stepv, candf, counts, (float*)d_out);
}